// Round 9
// baseline (203.274 us; speedup 1.0000x reference)
//
#include <hip/hip_runtime.h>

#define GAMMA 0.1f
#define MIN_R 0.1f

#define NRP 256                 // nodes per bin (power of 2)
#define LOG_NR 8
#define S3 (3 * NRP)            // floats per bin slice (768)
#define SEG 48                  // slots per (block,bin) segment
#define NBS 256                 // scatter blocks
#define THR_S 1024              // scatter threads
#define THR_P 1024              // process threads
#define RMAX 512                // max bins (n_nodes <= 131072)
#define OVCAP 131072            // overflow list capacity (edges)
#define CAPS (NBS * SEG)        // slots per bin (12288)

// ---------------- single-pass segmented scatter with x[src] prefetch ---------
// pk slot = 16 B payload {xs.x, xs.y, xs.z, u}. Bin r occupies slots
// [r*CAPS, (r+1)*CAPS); block b owns [r*CAPS + b*SEG, +SEG).
__global__ __launch_bounds__(THR_S) void scatter_kernel(
    const float* __restrict__ x,
    const int* __restrict__ src, const int* __restrict__ dst,
    unsigned* __restrict__ counts,   // [R][NBS]
    unsigned* __restrict__ oc, unsigned* __restrict__ ovf,
    uint4* __restrict__ pk,
    int n_edges, int epb, int R)
{
    __shared__ unsigned cur[RMAX];
    const int b = blockIdx.x, t = threadIdx.x;
    for (int i = t; i < R; i += THR_S) cur[i] = 0u;
    __syncthreads();

    const int s0 = b * epb;
    const int s1 = min(s0 + epb, n_edges);

    for (int base = s0 + t * 4; base < s1; base += THR_S * 4) {
        if (base + 3 < s1) {
            int4 d4 = *(const int4*)(dst + base);
            int4 s4 = *(const int4*)(src + base);
            int  sv[4] = {s4.x, s4.y, s4.z, s4.w};
            int  dv[4] = {d4.x, d4.y, d4.z, d4.w};
            unsigned pos[4];
            #pragma unroll
            for (int k = 0; k < 4; ++k)
                pos[k] = atomicAdd(&cur[(unsigned)dv[k] >> LOG_NR], 1u);
            // 4 independent gathers in flight (x is L2-resident)
            float3 xs[4];
            #pragma unroll
            for (int k = 0; k < 4; ++k)
                xs[k] = *(const float3*)(x + 3 * sv[k]);
            #pragma unroll
            for (int k = 0; k < 4; ++k) {
                unsigned d = (unsigned)dv[k];
                unsigned r = d >> LOG_NR;
                unsigned u = d & (NRP - 1);
                if (pos[k] < SEG) {
                    uint4 pl;
                    pl.x = __float_as_uint(xs[k].x);
                    pl.y = __float_as_uint(xs[k].y);
                    pl.z = __float_as_uint(xs[k].z);
                    pl.w = u;
                    pk[(size_t)r * CAPS + (size_t)b * SEG + pos[k]] = pl;
                } else {
                    unsigned oi = atomicAdd(oc, 1u);
                    if (oi < OVCAP) { ovf[2 * oi] = (unsigned)sv[k]; ovf[2 * oi + 1] = d; }
                }
            }
        } else {
            for (int e = base; e < s1; ++e) {
                unsigned d = (unsigned)dst[e];
                unsigned r = d >> LOG_NR;
                unsigned pos = atomicAdd(&cur[r], 1u);
                if (pos < SEG) {
                    float3 xs = *(const float3*)(x + 3 * src[e]);
                    uint4 pl;
                    pl.x = __float_as_uint(xs.x);
                    pl.y = __float_as_uint(xs.y);
                    pl.z = __float_as_uint(xs.z);
                    pl.w = d & (NRP - 1);
                    pk[(size_t)r * CAPS + (size_t)b * SEG + pos] = pl;
                } else {
                    unsigned oi = atomicAdd(oc, 1u);
                    if (oi < OVCAP) { ovf[2 * oi] = (unsigned)src[e]; ovf[2 * oi + 1] = d; }
                }
            }
        }
    }
    __syncthreads();
    for (int i = t; i < R; i += THR_S)
        counts[(size_t)i * NBS + b] = min(cur[i], (unsigned)SEG);
}

// ---------------- process: pure-stream per-bin LJ + direct out write ---------
__device__ __forceinline__ void lj_body(unsigned u, float3 xs,
                                        const float* __restrict__ xr,
                                        float* __restrict__ acc) {
    float dx = xr[3 * u + 0] - xs.x;
    float dy = xr[3 * u + 1] - xs.y;
    float dz = xr[3 * u + 2] - xs.z;
    float r2 = dx * dx + dy * dy + dz * dz;
    float rr = sqrtf(r2);
    float inv_norm = 1.0f / fmaxf(rr, 1e-12f);
    float rc = fmaxf(rr, MIN_R);
    float s1 = 1.0f / rc;                      // RC = 1
    float s2 = s1 * s1;
    float s6 = s2 * s2 * s2;
    float F = 4.0f * s6 * (12.0f * s6 - 6.0f) * s1;
    float sc = F * inv_norm;
    atomicAdd(&acc[3 * u + 0], sc * dx);
    atomicAdd(&acc[3 * u + 1], sc * dy);
    atomicAdd(&acc[3 * u + 2], sc * dz);
}

__global__ __launch_bounds__(THR_P) void process_kernel(
    const float* __restrict__ x, const float* __restrict__ v,
    const uint4* __restrict__ pk, const unsigned* __restrict__ counts,
    const unsigned* __restrict__ oc, const unsigned* __restrict__ ovf,
    float* __restrict__ out, int n_nodes)
{
    __shared__ __align__(16) float acc[S3];
    __shared__ __align__(16) float xr[S3];
    __shared__ unsigned cnts[NBS];
    const int r = blockIdx.x, t = threadIdx.x;
    const int xbase = 3 * r * NRP;
    const int xlim = 3 * n_nodes;
    for (int i = t; i < S3; i += THR_P) {
        acc[i] = 0.0f;
        int g = xbase + i;
        xr[i] = (g < xlim) ? x[g] : 0.0f;
    }
    for (int i = t; i < NBS; i += THR_P)
        cnts[i] = counts[(size_t)r * NBS + i];
    __syncthreads();

    // coalesced payload stream: no gathers
    const uint4* bin = pk + (size_t)r * CAPS;
    for (int slot = t; slot < CAPS; slot += THR_P) {
        const int seg = slot / SEG;
        const int idx = slot - seg * SEG;
        if (idx < (int)cnts[seg]) {
            uint4 q = bin[slot];
            float3 xs = make_float3(__uint_as_float(q.x), __uint_as_float(q.y),
                                    __uint_as_float(q.z));
            lj_body(q.w, xs, xr, acc);
        }
    }

    // overflow replay (normally tiny)
    const int noc = min((int)*oc, OVCAP);
    for (int i = t; i < noc; i += THR_P) {
        unsigned s = ovf[2 * i], d = ovf[2 * i + 1];
        if ((int)(d >> LOG_NR) == r) {
            float3 xs = *(const float3*)(x + 3 * s);
            lj_body(d & (NRP - 1), xs, xr, acc);
        }
    }
    __syncthreads();

    for (int i = t; i < S3; i += THR_P) {
        int g = xbase + i;
        if (g < xlim) out[g] = acc[i] - GAMMA * v[g];
    }
}

// ---------------- fallback path ----------------------------------------------
__global__ void init_out_kernel(const float* __restrict__ v,
                                float* __restrict__ out, int n) {
    int i = blockIdx.x * blockDim.x + threadIdx.x;
    if (i < n) out[i] = -GAMMA * v[i];
}

__global__ void edge_atomic_kernel(const float* __restrict__ x,
                                   const int* __restrict__ src,
                                   const int* __restrict__ dst,
                                   float* __restrict__ out, int n_edges) {
    int e = blockIdx.x * blockDim.x + threadIdx.x;
    if (e < n_edges) {
        int s = src[e], d = dst[e];
        float dx = x[3 * d + 0] - x[3 * s + 0];
        float dy = x[3 * d + 1] - x[3 * s + 1];
        float dz = x[3 * d + 2] - x[3 * s + 2];
        float rr = sqrtf(dx * dx + dy * dy + dz * dz);
        float inv_norm = 1.0f / fmaxf(rr, 1e-12f);
        float rc = fmaxf(rr, MIN_R);
        float s1 = 1.0f / rc;
        float s2 = s1 * s1;
        float s6 = s2 * s2 * s2;
        float F = 4.0f * s6 * (12.0f * s6 - 6.0f) * s1;
        float sc = F * inv_norm;
        unsafeAtomicAdd(&out[3 * d + 0], sc * dx);
        unsafeAtomicAdd(&out[3 * d + 1], sc * dy);
        unsafeAtomicAdd(&out[3 * d + 2], sc * dz);
    }
}

extern "C" void kernel_launch(void* const* d_in, const int* in_sizes, int n_in,
                              void* d_out, int out_size, void* d_ws, size_t ws_size,
                              hipStream_t stream) {
    const float* x   = (const float*)d_in[0];
    const float* v   = (const float*)d_in[1];
    const int*   src = (const int*)d_in[2];
    const int*   dst = (const int*)d_in[3];
    float* out = (float*)d_out;

    const int n_out = out_size;
    const int n_nodes = out_size / 3;
    const int n_edges = in_sizes[2];
    const int R = (n_nodes + NRP - 1) / NRP;

    size_t tables = ((size_t)R * NBS + 1 + 2 * (size_t)OVCAP) * 4;
    size_t pk_byte_off = (tables + 63) & ~(size_t)63;
    size_t need = pk_byte_off + (size_t)R * CAPS * 16;

    if (n_nodes <= (1 << 17) && R <= RMAX && need <= ws_size) {
        unsigned* counts = (unsigned*)d_ws;                  // R*NBS
        unsigned* oc     = counts + (size_t)R * NBS;         // 1
        unsigned* ovf    = oc + 1;                           // 2*OVCAP
        uint4*    pk     = (uint4*)((char*)d_ws + pk_byte_off);

        hipMemsetAsync(oc, 0, 4, stream);

        int epb = ((n_edges + NBS - 1) / NBS + 3) & ~3;
        scatter_kernel<<<NBS, THR_S, 0, stream>>>(x, src, dst, counts, oc, ovf,
                                                  pk, n_edges, epb, R);
        process_kernel<<<R, THR_P, 0, stream>>>(x, v, pk, counts, oc, ovf,
                                                out, n_nodes);
    } else {
        int blk = 256;
        init_out_kernel<<<(n_out + blk - 1) / blk, blk, 0, stream>>>(v, out, n_out);
        edge_atomic_kernel<<<(n_edges + blk - 1) / blk, blk, 0, stream>>>(
            x, src, dst, out, n_edges);
    }
}